// Round 3
// baseline (154.525 us; speedup 1.0000x reference)
//
#include <hip/hip_runtime.h>
#include <math.h>

// Problem constants (B=1, C=256, T=8, H=32, W=32, L=4, NUM_PTS=4, N_OFF=4)
#define CDIM 256
#define TDIM 8
#define HDIM 32
#define WDIM 32
#define LDIM 4
#define THW 8192
#define CSTR 32768            // T*H*W*L, per-channel stride in features
#define NS 64                 // NUM_PTS^3
#define OUT0_SIZE 8388608     // C*T*H*W*L

// uniform_flat_indices axes for T=8 / H=W=32, n=4 (round(linspace(hop/2, D-1-hop/2, 4)))
__device__ __constant__ int c_ti[4] = {1, 3, 4, 6};
__device__ __constant__ int c_hw[4] = {4, 12, 19, 27};

__device__ __forceinline__ float sigm(float x) { return 1.f / (1.f + expf(-x)); }

__device__ __forceinline__ float wave_sum64(float x) {
#pragma unroll
    for (int s = 32; s > 0; s >>= 1) x += __shfl_xor(x, s, 64);
    return x;
}

// ---- 1. Fill out with beta[c] + per-block partial feature sums (8 blocks/channel) ----
// HBM-bound (67 MB), 2048 blocks saturate BW. Unchanged.
__global__ void __launch_bounds__(256)
k_fill_part(const float* __restrict__ feat, const float* __restrict__ beta,
            float* __restrict__ out, float4* __restrict__ partF) {
    int c = blockIdx.x >> 3, part = blockIdx.x & 7;
    float bv = beta[c];
    float4 bf = make_float4(bv, bv, bv, bv);
    const float4* f = (const float4*)(feat + (size_t)c * CSTR) + part * 1024;
    float4* o = (float4*)(out + (size_t)c * CSTR) + part * 1024;
    float4 a = make_float4(0.f, 0.f, 0.f, 0.f);
#pragma unroll
    for (int it = 0; it < 4; ++it) {
        int i = it * 256 + threadIdx.x;
        float4 v = f[i];
        o[i] = bf;
        a.x += v.x; a.y += v.y; a.z += v.z; a.w += v.w;
    }
#pragma unroll
    for (int s = 32; s > 0; s >>= 1) {
        a.x += __shfl_xor(a.x, s, 64);
        a.y += __shfl_xor(a.y, s, 64);
        a.z += __shfl_xor(a.z, s, 64);
        a.w += __shfl_xor(a.w, s, 64);
    }
    __shared__ float4 sw[4];
    if ((threadIdx.x & 63) == 0) sw[threadIdx.x >> 6] = a;
    __syncthreads();
    if (threadIdx.x == 0) {
        float4 r;
        r.x = sw[0].x + sw[1].x + sw[2].x + sw[3].x;
        r.y = sw[0].y + sw[1].y + sw[2].y + sw[3].y;
        r.z = sw[0].z + sw[1].z + sw[2].z + sw[3].z;
        r.w = sw[0].w + sw[1].w + sw[2].w + sw[3].w;
        partF[blockIdx.x] = r;
    }
}

// ---- 2. One block = one site m: gather -> GEMV1 -> GEMV2 -> heads -> sample -> LN ----
// 256 blocks x 512 threads. No inter-block deps (GEMM output col m depends only on A col m).
// GEMV layout: wave kq = t>>6 owns a contiguous K-chunk; lanes j4 = t&63 own 4 columns.
// A[k] is an LDS broadcast; W row reads are 1KB fully-coalesced float4 per wave.
__global__ void __launch_bounds__(512)
k_rest(const float* __restrict__ feat, const float* __restrict__ pos,
       const float4* __restrict__ partF,
       const float* __restrict__ W1, const float* __restrict__ b1,
       const float* __restrict__ W2, const float* __restrict__ b2,
       const float* __restrict__ Wn, const float* __restrict__ bn,
       const float* __restrict__ Woff, const float* __restrict__ boff,
       const float* __restrict__ Ww, const float* __restrict__ bw,
       const float* __restrict__ gamma, const float* __restrict__ beta,
       float* __restrict__ out, float* __restrict__ next_out) {
    __shared__ float sA[768];          // A-vector for this site
    __shared__ float sRed[8][256];     // K-chunk partials
    __shared__ float sH[256];          // hidden layer
    __shared__ float sO[256];          // osrc row
    __shared__ float s_samp[4][3];
    __shared__ float s_wo[4];
    __shared__ float s_w[32];
    __shared__ int   s_o[32];
    __shared__ float red1[4], red2[4], redn[3][4];
    __shared__ float sPa[2][256];

    const int m = blockIdx.x, l = m >> 6, n = m & 63;
    const int t = threadIdx.x;
    const int sp = (c_ti[n >> 4] * HDIM + c_hw[(n >> 2) & 3]) * WDIM + c_hw[n & 3];

    // ---- Phase A: gather A[768] = [feat | pos | glob] at this site ----
    {
        int c = t & 255;
        if (t < 256) {
            sA[c] = feat[(size_t)c * CSTR + sp * LDIM + l];
            float s = 0.f;
#pragma unroll
            for (int p = 0; p < 8; ++p) {
                float4 v = partF[c * 8 + p];
                s += (l == 0) ? v.x : (l == 1) ? v.y : (l == 2) ? v.z : v.w;
            }
            sA[512 + c] = s * (1.f / 8192.f);
        } else {
            sA[256 + c] = pos[(size_t)c * CSTR + sp * LDIM + l];
        }
    }
    __syncthreads();

    // ---- Phase B: h1 = relu(b1 + A @ W1), K=768: 8 waves x 96-k chunks ----
    {
        int j4 = t & 63, kq = t >> 6;
        const float4* Wp = (const float4*)W1 + (size_t)(kq * 96) * 64 + j4;
        float ax = 0.f, ay = 0.f, az = 0.f, aw = 0.f;
#pragma unroll 8
        for (int kk = 0; kk < 96; ++kk) {
            float a = sA[kq * 96 + kk];
            float4 w = Wp[(size_t)kk * 64];
            ax = fmaf(a, w.x, ax); ay = fmaf(a, w.y, ay);
            az = fmaf(a, w.z, az); aw = fmaf(a, w.w, aw);
        }
        *(float4*)&sRed[kq][j4 * 4] = make_float4(ax, ay, az, aw);
    }
    __syncthreads();
    if (t < 256) {
        float v = b1[t];
#pragma unroll
        for (int q = 0; q < 8; ++q) v += sRed[q][t];
        sH[t] = fmaxf(v, 0.f);
    }
    __syncthreads();

    // ---- Phase C: osrc = relu(b2 + h1 @ W2), K=256: 8 waves x 32-k chunks ----
    {
        int j4 = t & 63, kq = t >> 6;
        const float4* Wp = (const float4*)W2 + (size_t)(kq * 32) * 64 + j4;
        float ax = 0.f, ay = 0.f, az = 0.f, aw = 0.f;
#pragma unroll 8
        for (int kk = 0; kk < 32; ++kk) {
            float a = sH[kq * 32 + kk];
            float4 w = Wp[(size_t)kk * 64];
            ax = fmaf(a, w.x, ax); ay = fmaf(a, w.y, ay);
            az = fmaf(a, w.z, az); aw = fmaf(a, w.w, aw);
        }
        *(float4*)&sRed[kq][j4 * 4] = make_float4(ax, ay, az, aw);
    }
    __syncthreads();
    if (t < 256) {
        float v = b2[t];
#pragma unroll
        for (int q = 0; q < 8; ++q) v += sRed[q][t];
        sO[t] = fmaxf(v, 0.f);
    }
    __syncthreads();

    // ---- Phase D: heads (nxt, offset, w_o) from osrc in LDS ----
    if (t < 256) {
        int j = t, o = j >> 6, r = j & 63;
        float v = sO[j];

        // nxt = osrc @ Wn (full-256 reduction via per-wave partials)
        float pn0 = wave_sum64(v * Wn[j * 3 + 0]);
        float pn1 = wave_sum64(v * Wn[j * 3 + 1]);
        float pn2 = wave_sum64(v * Wn[j * 3 + 2]);
        if (r == 0) { redn[0][o] = pn0; redn[1][o] = pn1; redn[2][o] = pn2; }

        // per-o heads (d=64): offset and w_o
        float po0 = wave_sum64(v * Woff[r * 3 + 0]);
        float po1 = wave_sum64(v * Woff[r * 3 + 1]);
        float po2 = wave_sum64(v * Woff[r * 3 + 2]);
        float z0  = wave_sum64(v * Ww[r * 2 + 0]);
        float z1  = wave_sum64(v * Ww[r * 2 + 1]);

        if (r == 0) {
            float tn = (float)c_ti[n >> 4] / 7.f;
            float hn = (float)c_hw[(n >> 2) & 3] / 31.f;
            float wn = (float)c_hw[n & 3] / 31.f;
            float lg0 = logf(tn / (1.f - tn));
            float lg1 = logf(hn / (1.f - hn));
            float lg2 = logf(wn / (1.f - wn));
            s_samp[o][0] = sigm(lg0 + po0 + boff[0]) * 2.f - 1.f;
            s_samp[o][1] = sigm(lg1 + po1 + boff[1]) * 2.f - 1.f;
            s_samp[o][2] = sigm(lg2 + po2 + boff[2]) * 2.f - 1.f;
            s_wo[o] = 1.f / (1.f + expf((z0 + bw[0]) - (z1 + bw[1])));   // softmax[...,1]
        }
    }
    __syncthreads();

    if (t == 0) {
        float tn = (float)c_ti[n >> 4] / 7.f;
        float hn = (float)c_hw[(n >> 2) & 3] / 31.f;
        float wn = (float)c_hw[n & 3] / 31.f;
        float lg0 = logf(tn / (1.f - tn));
        float lg1 = logf(hn / (1.f - hn));
        float lg2 = logf(wn / (1.f - wn));
        float t0 = redn[0][0] + redn[0][1] + redn[0][2] + redn[0][3];
        float t1 = redn[1][0] + redn[1][1] + redn[1][2] + redn[1][3];
        float t2 = redn[2][0] + redn[2][1] + redn[2][2] + redn[2][3];
        float d0 = rintf(sigm(lg0 + t0 + bn[0]) * 7.f);
        float d1 = rintf(sigm(lg1 + t1 + bn[1]) * 31.f);
        float d2 = rintf(sigm(lg2 + t2 + bn[2]) * 31.f);
        next_out[m] = 1024.f * d0 + 32.f * d1 + d2;   // H*W*d0 + W*d1 + d2
    }

    if (t < 4) {
        int oo = t;
        float wv = s_wo[oo];
        float g0 = s_samp[oo][0], g1 = s_samp[oo][1], g2 = s_samp[oo][2];
        // reference grid_sample: ch0 -> x over W, ch1 -> y over H, ch2 -> z over D(=T)
        float ix = ((g0 + 1.f) * 32.f - 1.f) * 0.5f;
        float iy = ((g1 + 1.f) * 32.f - 1.f) * 0.5f;
        float iz = ((g2 + 1.f) * 8.f  - 1.f) * 0.5f;
        float x0f = floorf(ix), y0f = floorf(iy), z0f = floorf(iz);
        float fx = ix - x0f, fy = iy - y0f, fz = iz - z0f;
        int x0 = (int)x0f, y0 = (int)y0f, z0 = (int)z0f;
#pragma unroll
        for (int k = 0; k < 8; ++k) {
            int dx = k & 1, dy = (k >> 1) & 1, dz = k >> 2;
            int xi = x0 + dx, yi = y0 + dy, zi = z0 + dz;
            float w = (dx ? fx : 1.f - fx) * (dy ? fy : 1.f - fy) * (dz ? fz : 1.f - fz);
            bool valid = (xi >= 0) && (xi < WDIM) && (yi >= 0) && (yi < HDIM) && (zi >= 0) && (zi < TDIM);
            int xc = min(max(xi, 0), WDIM - 1);
            int yc = min(max(yi, 0), HDIM - 1);
            int zc = min(max(zi, 0), TDIM - 1);
            s_w[oo * 8 + k] = valid ? w * wv : 0.f;
            s_o[oo * 8 + k] = ((zc * HDIM + yc) * WDIM + xc) * LDIM + l;
        }
    }
    __syncthreads();

    // ---- Phase E: sampling gather (2 threads/channel split 33 taps) + LayerNorm ----
    {
        int c = t & 255, h = t >> 8;
        const float* fc = feat + (size_t)c * CSTR;
        float vals[16];
        int base = h * 16;
#pragma unroll
        for (int k = 0; k < 16; ++k) vals[k] = fc[s_o[base + k]];
        float acc = (h == 0) ? fc[sp * LDIM + l] : 0.f;
#pragma unroll
        for (int k = 0; k < 16; ++k) acc += s_w[base + k] * vals[k];
        sPa[h][c] = acc;
    }
    __syncthreads();

    float accf = 0.f;
    if (t < 256) {
        accf = sPa[0][t] + sPa[1][t];
        // LayerNorm over C=256
        float s1 = accf, s2 = accf * accf;
#pragma unroll
        for (int d = 32; d > 0; d >>= 1) { s1 += __shfl_xor(s1, d, 64); s2 += __shfl_xor(s2, d, 64); }
        int wid = t >> 6;
        if ((t & 63) == 0) { red1[wid] = s1; red2[wid] = s2; }
    }
    __syncthreads();
    if (t < 256) {
        int c = t;
        float tot  = red1[0] + red1[1] + red1[2] + red1[3];
        float totq = red2[0] + red2[1] + red2[2] + red2[3];
        float mu = tot * (1.f / 256.f);
        float var = fmaxf(totq * (1.f / 256.f) - mu * mu, 0.f);
        float y = (accf - mu) * rsqrtf(var + 1e-5f) * gamma[c] + beta[c];
        out[(size_t)c * CSTR + sp * LDIM + l] = y;
    }
}

extern "C" void kernel_launch(void* const* d_in, const int* in_sizes, int n_in,
                              void* d_out, int out_size, void* d_ws, size_t ws_size,
                              hipStream_t stream) {
    const float* feat = (const float*)d_in[0];
    const float* pos  = (const float*)d_in[1];
    const float* W1   = (const float*)d_in[2];
    const float* b1   = (const float*)d_in[3];
    const float* W2   = (const float*)d_in[4];
    const float* b2   = (const float*)d_in[5];
    const float* Wn   = (const float*)d_in[6];
    const float* bn   = (const float*)d_in[7];
    // d_in[8]=Wl, d_in[9]=bl provably unused (softmax rows sum to 1)
    const float* Woff = (const float*)d_in[10];
    const float* boff = (const float*)d_in[11];
    const float* Ww   = (const float*)d_in[12];
    const float* bw   = (const float*)d_in[13];
    const float* gamma= (const float*)d_in[14];
    const float* beta = (const float*)d_in[15];
    float* out = (float*)d_out;
    float* next_out = out + OUT0_SIZE;

    float4* partF = (float4*)d_ws;          // 2048 float4

    k_fill_part<<<2048, 256, 0, stream>>>(feat, beta, out, partF);
    k_rest<<<256, 512, 0, stream>>>(feat, pos, partF, W1, b1, W2, b2, Wn, bn,
                                    Woff, boff, Ww, bw, gamma, beta, out, next_out);
}